// Round 8
// baseline (151.680 us; speedup 1.0000x reference)
//
#include <hip/hip_runtime.h>
#include <hip/hip_bf16.h>
#include <math.h>

// OHEM BCE-with-logits, (4,1,192,192,192) f32 -> scalar f32.
//
// R8: R7's sampled-threshold algorithm with (a) PERFECTLY COALESCED loads
// (lane-contiguous float4, 1KB/instr; R3-R7's 2-adjacent-float4 pattern gave
// each instr a 32B lane stride = 32 half-used cachelines, suspected to waste
// line-granular MSHR slots and halve streaming BW), and (b) 4 kernels fused
// to 2 via last-block finalization (threadfence + done counter).
//
//  A: 1/64-sampled 1024-bin histogram of negative logits -> threshold thr
//  B: full pass, 4 register accumulators (n_pos, pos_sum, cnt/sum of
//     negatives with x >= thr); last block: neg_sum = asum +
//     (k - acnt)*softplus(thr); out = pos_mean + neg_sum/k.

typedef unsigned int uint;

#define NBIN_A 1024
#define XMINF  -8.0f
#define ASCALE 64.0f          // (x+8)*64 -> [0,1024)
#define INV_ASCALE 0.015625f
#define GB_A 432              // sample blocks
#define GB 1728               // main blocks
#define TB 256
#define GTH (GB * TB)         // 442368 threads; n4 = 16*GTH exactly
#define INV64 0.015625f

__device__ __forceinline__ float softplus_f(float v) {
    return fmaxf(v, 0.0f) + log1pf(expf(-fabsf(v)));
}

// ---- A: sampled histogram + threshold (fused via last-block) ----
extern "C" __global__ __launch_bounds__(256) void ohem_sample_thresh(
    const float4* __restrict__ L4, const float4* __restrict__ T4,
    uint* g_hist, uint* g_nneg, float* g_thr, uint* doneA)
{
    __shared__ uint h[NBIN_A];
    __shared__ uint s_cnt[4];
    __shared__ uint s_rank;
    __shared__ uint sh_c[256];
    __shared__ uint suf[256];
    __shared__ float s_ks;
    __shared__ float s_thr;

    int tid = threadIdx.x;
    for (int i = tid; i < NBIN_A; i += 256) h[i] = 0u;
    __syncthreads();

    int gid = blockIdx.x * 256 + tid;
    int wv = gid >> 6, lane = gid & 63;
    size_t g = (size_t)wv * 4096 + lane;      // 1KB contiguous per wave
    float4 x4 = L4[g];
    float4 t4 = T4[g];
    float xs[4] = {x4.x, x4.y, x4.z, x4.w};
    float ts[4] = {t4.x, t4.y, t4.z, t4.w};
    uint nneg = 0;
    #pragma unroll
    for (int j = 0; j < 4; ++j) {
        if (ts[j] <= 0.5f) {
            nneg++;
            float f = fmaxf(fmaf(xs[j], ASCALE, -XMINF * ASCALE), 0.0f);
            uint b = (uint)f;
            b = b > NBIN_A - 1 ? NBIN_A - 1 : b;
            atomicAdd(&h[b], 1u);
        }
    }
    __syncthreads();
    for (int i = tid; i < NBIN_A; i += 256) {
        uint c = h[i];
        if (c) atomicAdd(&g_hist[i], c);
    }
    #pragma unroll
    for (int off = 32; off > 0; off >>= 1) nneg += __shfl_down(nneg, off);
    if ((tid & 63) == 0) s_cnt[tid >> 6] = nneg;
    __syncthreads();
    if (tid == 0) {
        uint c = s_cnt[0] + s_cnt[1] + s_cnt[2] + s_cnt[3];
        if (c) atomicAdd(g_nneg, c);
        __threadfence();
        s_rank = atomicAdd(doneA, 1u);
    }
    __syncthreads();
    if (s_rank != GB_A - 1) return;

    // ---- last block: derive threshold (atomic reads for coherence) ----
    uint lc[4];
    uint tc = 0;
    #pragma unroll
    for (int j = 0; j < 4; ++j) {
        lc[j] = atomicAdd(&g_hist[tid * 4 + j], 0u);
        tc += lc[j];
    }
    sh_c[tid] = tc;
    __syncthreads();
    if (tid == 0) {
        uint rc = 0;
        for (int i = 255; i >= 0; --i) { suf[i] = rc; rc += sh_c[i]; }
        float nneg64 = 64.0f * (float)atomicAdd(g_nneg, 0u);
        float kest = rintf(0.1f * nneg64);
        if (kest < 1024.0f) kest = 1024.0f;
        s_ks = kest * INV64;                  // sampled-scale rank target
        s_thr = XMINF;                        // fallback: select all
    }
    __syncthreads();
    float ks = s_ks;
    float run = (float)suf[tid];
    #pragma unroll
    for (int j = 3; j >= 0; --j) {
        float c = (float)lc[j];
        if (c > 0.0f && run < ks && run + c >= ks)
            s_thr = XMINF + (float)(tid * 4 + j) * INV_ASCALE;
        run += c;
    }
    __syncthreads();
    if (tid == 0) *g_thr = s_thr;
}

// ---- B: main accumulation + final (fused via last-block) ----
extern "C" __global__ __launch_bounds__(256) void ohem_main_final(
    const float4* __restrict__ L4, const float4* __restrict__ T4,
    const float* __restrict__ g_thr,
    uint* g_pcnt, float* g_psum, uint* g_acnt, float* g_asum,
    uint* doneB, float* out, int n_total)
{
    __shared__ uint s_pc[4];
    __shared__ float s_ps[4];
    __shared__ uint s_ac[4];
    __shared__ float s_as[4];
    __shared__ uint s_rank;

    const float thr = *g_thr;
    const int g0 = blockIdx.x * TB + threadIdx.x;
    uint pcnt = 0, acnt = 0;
    float psum = 0.0f, asum = 0.0f;

#define EL(xx, tt) {                                                        \
    float x = (xx);                                                         \
    float sp = fmaxf(x, 0.0f) + __logf(1.0f + __expf(-fabsf(x)));           \
    bool pos = (tt) > 0.5f;                                                 \
    bool sel = (x >= thr) && !pos;                                          \
    pcnt += pos ? 1u : 0u;                                                  \
    psum += pos ? (sp - x) : 0.0f;  /* softplus(-x) = softplus(x) - x */    \
    acnt += sel ? 1u : 0u;                                                  \
    asum += sel ? sp : 0.0f; }

    for (int o = 0; o < 4; ++o) {
        int i0 = g0 + (4 * o + 0) * GTH;
        int i1 = g0 + (4 * o + 1) * GTH;
        int i2 = g0 + (4 * o + 2) * GTH;
        int i3 = g0 + (4 * o + 3) * GTH;
        // 8 perfectly-coalesced 16B/lane loads issued before any consume
        float4 xv0 = L4[i0], xv1 = L4[i1], xv2 = L4[i2], xv3 = L4[i3];
        float4 tv0 = T4[i0], tv1 = T4[i1], tv2 = T4[i2], tv3 = T4[i3];
        EL(xv0.x, tv0.x) EL(xv0.y, tv0.y) EL(xv0.z, tv0.z) EL(xv0.w, tv0.w)
        EL(xv1.x, tv1.x) EL(xv1.y, tv1.y) EL(xv1.z, tv1.z) EL(xv1.w, tv1.w)
        EL(xv2.x, tv2.x) EL(xv2.y, tv2.y) EL(xv2.z, tv2.z) EL(xv2.w, tv2.w)
        EL(xv3.x, tv3.x) EL(xv3.y, tv3.y) EL(xv3.z, tv3.z) EL(xv3.w, tv3.w)
    }
#undef EL

    #pragma unroll
    for (int off = 32; off > 0; off >>= 1) {
        pcnt += __shfl_down(pcnt, off);
        psum += __shfl_down(psum, off);
        acnt += __shfl_down(acnt, off);
        asum += __shfl_down(asum, off);
    }
    int wv = threadIdx.x >> 6;
    if ((threadIdx.x & 63) == 0) {
        s_pc[wv] = pcnt; s_ps[wv] = psum;
        s_ac[wv] = acnt; s_as[wv] = asum;
    }
    __syncthreads();
    if (threadIdx.x == 0) {
        uint pc = s_pc[0] + s_pc[1] + s_pc[2] + s_pc[3];
        float ps = s_ps[0] + s_ps[1] + s_ps[2] + s_ps[3];
        uint ac = s_ac[0] + s_ac[1] + s_ac[2] + s_ac[3];
        float as = s_as[0] + s_as[1] + s_as[2] + s_as[3];
        if (pc) atomicAdd(g_pcnt, pc);
        atomicAdd(g_psum, ps);
        if (ac) atomicAdd(g_acnt, ac);
        atomicAdd(g_asum, as);
        __threadfence();
        s_rank = atomicAdd(doneB, 1u);
    }
    __syncthreads();
    if (s_rank != GB - 1) return;

    // ---- last block: finalize scalar ----
    if (threadIdx.x == 0) {
        uint npos = atomicAdd(g_pcnt, 0u);
        float psv = atomicAdd(g_psum, 0.0f);
        uint ac   = atomicAdd(g_acnt, 0u);
        float asv = atomicAdd(g_asum, 0.0f);
        uint nneg = (uint)n_total - npos;
        float pos_mean = npos ? (psv / (float)npos) : 0.0f;
        float res;
        if (nneg == 0) {
            res = pos_mean;
        } else {
            float nf = (float)nneg;          // RNE, matches .astype(f32)
            float kf = rintf(0.1f * nf);     // RNE, matches jnp.round
            if (kf < 1024.0f) kf = 1024.0f;
            if (kf > nf) kf = nf;
            float spt = softplus_f(thr);
            float neg_sum = asv + (kf - (float)ac) * spt;  // boundary corr.
            res = pos_mean + neg_sum / kf;
        }
        out[0] = res;
    }
}

extern "C" void kernel_launch(void* const* d_in, const int* in_sizes, int n_in,
                              void* d_out, int out_size, void* d_ws, size_t ws_size,
                              hipStream_t stream) {
    const float4* L4 = (const float4*)d_in[0];
    const float4* T4 = (const float4*)d_in[1];
    float* out = (float*)d_out;
    int n_total = in_sizes[0];

    // ws layout (bytes): hist[1024] @0, nneg @4096, thr @4100, pcnt @4104,
    // psum @4108, acnt @4112, asum @4116, doneA @4120, doneB @4124
    uint*  g_hist = (uint*)d_ws;
    uint*  g_nneg = (uint*)((char*)d_ws + 4096);
    float* g_thr  = (float*)((char*)d_ws + 4100);
    uint*  g_pcnt = (uint*)((char*)d_ws + 4104);
    float* g_psum = (float*)((char*)d_ws + 4108);
    uint*  g_acnt = (uint*)((char*)d_ws + 4112);
    float* g_asum = (float*)((char*)d_ws + 4116);
    uint*  doneA  = (uint*)((char*)d_ws + 4120);
    uint*  doneB  = (uint*)((char*)d_ws + 4124);

    hipMemsetAsync(d_ws, 0, 4128, stream);

    ohem_sample_thresh<<<GB_A, TB, 0, stream>>>(L4, T4, g_hist, g_nneg,
                                                g_thr, doneA);
    ohem_main_final<<<GB, TB, 0, stream>>>(L4, T4, g_thr,
                                           g_pcnt, g_psum, g_acnt, g_asum,
                                           doneB, out, n_total);
}

// Round 9
// 144.669 us; speedup vs baseline: 1.0485x; 1.0485x over previous
//
#include <hip/hip_runtime.h>
#include <hip/hip_bf16.h>
#include <math.h>

// OHEM BCE-with-logits, (4,1,192,192,192) f32 -> scalar f32.
//
// R9: sampled-threshold algorithm (R7/R8, absmax 0.0) with BLOCK-CONTIGUOUS
// streaming. R8 proved 64KB-multiple strides between concurrent loads kill
// HBM channel parallelism (670 GB/s); R3-R7's 32B-lane-stride made every
// load instruction cover half-lines. Here: 1536 blocks x 256 thr; block b
// owns float4 range [b*4608, (b+1)*4608) -- a contiguous 72KB chunk per
// array (non-power-of-2 start offsets = good channel spread). Per iteration
// a wave holds 4x 1KB fully-used contiguous loads in flight (L[i], L[i+256],
// T[i], T[i+256]).
//
//  A: 1/64-sampled 1024-bin histogram of negative logits -> threshold thr
//  B: full pass, 4 register accumulators (n_pos, pos_sum, cnt/sum of
//     negatives with x >= thr); last block folds: neg_sum = asum +
//     (k - acnt)*softplus(thr); out = pos_mean + neg_sum/k.

typedef unsigned int uint;

#define NBIN_A 1024
#define XMINF  -8.0f
#define ASCALE 64.0f          // (x+8)*64 -> [0,1024)
#define INV_ASCALE 0.015625f
#define GB_A 432              // sample blocks
#define GB 1536               // main blocks: 6/CU, chunk = 4608 float4
#define TB 256
#define INV64 0.015625f

__device__ __forceinline__ float softplus_f(float v) {
    return fmaxf(v, 0.0f) + log1pf(expf(-fabsf(v)));
}

// ---- A: sampled histogram + threshold (fused via last-block) ----
extern "C" __global__ __launch_bounds__(256) void ohem_sample_thresh(
    const float4* __restrict__ L4, const float4* __restrict__ T4,
    uint* g_hist, uint* g_nneg, float* g_thr, uint* doneA)
{
    __shared__ uint h[NBIN_A];
    __shared__ uint s_cnt[4];
    __shared__ uint s_rank;
    __shared__ uint sh_c[256];
    __shared__ uint suf[256];
    __shared__ float s_ks;
    __shared__ float s_thr;

    int tid = threadIdx.x;
    for (int i = tid; i < NBIN_A; i += 256) h[i] = 0u;
    __syncthreads();

    int gid = blockIdx.x * 256 + tid;
    int wv = gid >> 6, lane = gid & 63;
    size_t g = (size_t)wv * 4096 + lane;      // 1KB contiguous per wave
    float4 x4 = L4[g];
    float4 t4 = T4[g];
    float xs[4] = {x4.x, x4.y, x4.z, x4.w};
    float ts[4] = {t4.x, t4.y, t4.z, t4.w};
    uint nneg = 0;
    #pragma unroll
    for (int j = 0; j < 4; ++j) {
        if (ts[j] <= 0.5f) {
            nneg++;
            float f = fmaxf(fmaf(xs[j], ASCALE, -XMINF * ASCALE), 0.0f);
            uint b = (uint)f;
            b = b > NBIN_A - 1 ? NBIN_A - 1 : b;
            atomicAdd(&h[b], 1u);
        }
    }
    __syncthreads();
    for (int i = tid; i < NBIN_A; i += 256) {
        uint c = h[i];
        if (c) atomicAdd(&g_hist[i], c);
    }
    #pragma unroll
    for (int off = 32; off > 0; off >>= 1) nneg += __shfl_down(nneg, off);
    if ((tid & 63) == 0) s_cnt[tid >> 6] = nneg;
    __syncthreads();
    if (tid == 0) {
        uint c = s_cnt[0] + s_cnt[1] + s_cnt[2] + s_cnt[3];
        if (c) atomicAdd(g_nneg, c);
        __threadfence();
        s_rank = atomicAdd(doneA, 1u);
    }
    __syncthreads();
    if (s_rank != GB_A - 1) return;

    // ---- last block: derive threshold (atomic reads for coherence) ----
    uint lc[4];
    uint tc = 0;
    #pragma unroll
    for (int j = 0; j < 4; ++j) {
        lc[j] = atomicAdd(&g_hist[tid * 4 + j], 0u);
        tc += lc[j];
    }
    sh_c[tid] = tc;
    __syncthreads();
    if (tid == 0) {
        uint rc = 0;
        for (int i = 255; i >= 0; --i) { suf[i] = rc; rc += sh_c[i]; }
        float nneg64 = 64.0f * (float)atomicAdd(g_nneg, 0u);
        float kest = rintf(0.1f * nneg64);
        if (kest < 1024.0f) kest = 1024.0f;
        s_ks = kest * INV64;                  // sampled-scale rank target
        s_thr = XMINF;                        // fallback: select all
    }
    __syncthreads();
    float ks = s_ks;
    float run = (float)suf[tid];
    #pragma unroll
    for (int j = 3; j >= 0; --j) {
        float c = (float)lc[j];
        if (c > 0.0f && run < ks && run + c >= ks)
            s_thr = XMINF + (float)(tid * 4 + j) * INV_ASCALE;
        run += c;
    }
    __syncthreads();
    if (tid == 0) *g_thr = s_thr;
}

// ---- B: main accumulation + final (fused via last-block) ----
extern "C" __global__ __launch_bounds__(256) void ohem_main_final(
    const float4* __restrict__ L4, const float4* __restrict__ T4,
    const float* __restrict__ g_thr,
    uint* g_pcnt, float* g_psum, uint* g_acnt, float* g_asum,
    uint* doneB, float* out, int n_total, int n4)
{
    __shared__ uint s_pc[4];
    __shared__ float s_ps[4];
    __shared__ uint s_ac[4];
    __shared__ float s_as[4];
    __shared__ uint s_rank;

    const float thr = *g_thr;
    const int tid = threadIdx.x;
    const int chunk = n4 / GB;                 // 4608 for this shape
    const int start = blockIdx.x * chunk;
    const int end = (blockIdx.x == GB - 1) ? n4 : (start + chunk);

    uint pcnt = 0, acnt = 0;
    float psum = 0.0f, asum = 0.0f;

#define EL(xx, tt) {                                                        \
    float x = (xx);                                                         \
    float sp = fmaxf(x, 0.0f) + __logf(1.0f + __expf(-fabsf(x)));           \
    bool pos = (tt) > 0.5f;                                                 \
    bool sel = (x >= thr) && !pos;                                          \
    pcnt += pos ? 1u : 0u;                                                  \
    psum += pos ? (sp - x) : 0.0f;  /* softplus(-x) = softplus(x) - x */    \
    acnt += sel ? 1u : 0u;                                                  \
    asum += sel ? sp : 0.0f; }

    int i = start + tid;
    // pair-unrolled: 4 fully-coalesced 1KB loads in flight per wave,
    // addresses contiguous within an 8KB window of each array
    for (; i + TB < end; i += 2 * TB) {
        float4 xa = L4[i], xb = L4[i + TB];
        float4 ta = T4[i], tb = T4[i + TB];
        EL(xa.x, ta.x) EL(xa.y, ta.y) EL(xa.z, ta.z) EL(xa.w, ta.w)
        EL(xb.x, tb.x) EL(xb.y, tb.y) EL(xb.z, tb.z) EL(xb.w, tb.w)
    }
    if (i < end) {                             // odd-iteration tail
        float4 xa = L4[i];
        float4 ta = T4[i];
        EL(xa.x, ta.x) EL(xa.y, ta.y) EL(xa.z, ta.z) EL(xa.w, ta.w)
    }
    // scalar tail for n_total % 4 != 0 -- empty for this shape
    if (blockIdx.x == GB - 1) {
        for (int t = n4 * 4 + tid; t < n_total; t += TB) {
            const float* Lf = (const float*)L4;
            const float* Tf = (const float*)T4;
            EL(Lf[t], Tf[t])
        }
    }
#undef EL

    #pragma unroll
    for (int off = 32; off > 0; off >>= 1) {
        pcnt += __shfl_down(pcnt, off);
        psum += __shfl_down(psum, off);
        acnt += __shfl_down(acnt, off);
        asum += __shfl_down(asum, off);
    }
    int wv = tid >> 6;
    if ((tid & 63) == 0) {
        s_pc[wv] = pcnt; s_ps[wv] = psum;
        s_ac[wv] = acnt; s_as[wv] = asum;
    }
    __syncthreads();
    if (tid == 0) {
        uint pc = s_pc[0] + s_pc[1] + s_pc[2] + s_pc[3];
        float ps = s_ps[0] + s_ps[1] + s_ps[2] + s_ps[3];
        uint ac = s_ac[0] + s_ac[1] + s_ac[2] + s_ac[3];
        float as = s_as[0] + s_as[1] + s_as[2] + s_as[3];
        if (pc) atomicAdd(g_pcnt, pc);
        atomicAdd(g_psum, ps);
        if (ac) atomicAdd(g_acnt, ac);
        atomicAdd(g_asum, as);
        __threadfence();
        s_rank = atomicAdd(doneB, 1u);
    }
    __syncthreads();
    if (s_rank != GB - 1) return;

    // ---- last finishing block: fold the scalar ----
    if (tid == 0) {
        uint npos = atomicAdd(g_pcnt, 0u);
        float psv = atomicAdd(g_psum, 0.0f);
        uint ac   = atomicAdd(g_acnt, 0u);
        float asv = atomicAdd(g_asum, 0.0f);
        uint nneg = (uint)n_total - npos;
        float pos_mean = npos ? (psv / (float)npos) : 0.0f;
        float res;
        if (nneg == 0) {
            res = pos_mean;
        } else {
            float nf = (float)nneg;          // RNE, matches .astype(f32)
            float kf = rintf(0.1f * nf);     // RNE, matches jnp.round
            if (kf < 1024.0f) kf = 1024.0f;
            if (kf > nf) kf = nf;
            float spt = softplus_f(thr);
            float neg_sum = asv + (kf - (float)ac) * spt;  // boundary corr.
            res = pos_mean + neg_sum / kf;
        }
        out[0] = res;
    }
}

extern "C" void kernel_launch(void* const* d_in, const int* in_sizes, int n_in,
                              void* d_out, int out_size, void* d_ws, size_t ws_size,
                              hipStream_t stream) {
    const float4* L4 = (const float4*)d_in[0];
    const float4* T4 = (const float4*)d_in[1];
    float* out = (float*)d_out;
    int n_total = in_sizes[0];
    int n4 = n_total / 4;

    // ws layout (bytes): hist[1024] @0, nneg @4096, thr @4100, pcnt @4104,
    // psum @4108, acnt @4112, asum @4116, doneA @4120, doneB @4124
    uint*  g_hist = (uint*)d_ws;
    uint*  g_nneg = (uint*)((char*)d_ws + 4096);
    float* g_thr  = (float*)((char*)d_ws + 4100);
    uint*  g_pcnt = (uint*)((char*)d_ws + 4104);
    float* g_psum = (float*)((char*)d_ws + 4108);
    uint*  g_acnt = (uint*)((char*)d_ws + 4112);
    float* g_asum = (float*)((char*)d_ws + 4116);
    uint*  doneA  = (uint*)((char*)d_ws + 4120);
    uint*  doneB  = (uint*)((char*)d_ws + 4124);

    hipMemsetAsync(d_ws, 0, 4128, stream);

    ohem_sample_thresh<<<GB_A, TB, 0, stream>>>(L4, T4, g_hist, g_nneg,
                                                g_thr, doneA);
    ohem_main_final<<<GB, TB, 0, stream>>>(L4, T4, g_thr,
                                           g_pcnt, g_psum, g_acnt, g_asum,
                                           doneB, out, n_total, n4);
}

// Round 10
// 84.330 us; speedup vs baseline: 1.7986x; 1.7155x over previous
//
#include <hip/hip_runtime.h>
#include <hip/hip_bf16.h>
#include <math.h>

// OHEM BCE-with-logits, (4,1,192,192,192) f32 -> scalar f32.
//
// R10: minimum-dispatch assembly of the empirically fastest components.
// Evidence R1-R9: the ONLY fast streaming pattern on this op is the
// grid-stride 1024-thread loop with 2-ADJACENT-float4 per lane (32B lane
// stride): ~4.2 TB/s effective. Both fully-coalesced variants (R8 stride
// 2^n, R9 block-contiguous) ran 2x slower and thrashed L3 on replays.
// So: keep R7's exact main-loop shape; cut dispatches 5 -> 3 by fusing
// threshold-derivation into the sample kernel's last block (R8, verified)
// and the final fold into the main kernel's last block.
//
//  A: 1/64-sampled 1024-bin histogram of negative logits -> threshold thr
//  B: full 226MB pass, 4 register accumulators (n_pos, pos_sum, cnt/sum of
//     negatives with x >= thr); last block: neg_sum = asum +
//     (k - acnt)*softplus(thr); out = pos_mean + neg_sum/k.
//     Boundary-band approximation error ~1e-5 << 5.5e-2 tolerance.

typedef unsigned int uint;

#define NBIN_A 1024
#define XMINF  -8.0f
#define ASCALE 64.0f          // (x+8)*64 -> [0,1024)
#define INV_ASCALE 0.015625f
#define GB_A 432              // sample blocks
#define GB_M 512              // main blocks (1024 thr: 2/CU, full residency)
#define INV64 0.015625f

__device__ __forceinline__ float softplus_f(float v) {
    return fmaxf(v, 0.0f) + log1pf(expf(-fabsf(v)));
}

// ---- A: sampled histogram + threshold (fused via last-block) ----
extern "C" __global__ __launch_bounds__(256) void ohem_sample_thresh(
    const float4* __restrict__ L4, const float4* __restrict__ T4,
    uint* g_hist, uint* g_nneg, float* g_thr, uint* doneA)
{
    __shared__ uint h[NBIN_A];
    __shared__ uint s_cnt[4];
    __shared__ uint s_rank;
    __shared__ uint sh_c[256];
    __shared__ uint suf[256];
    __shared__ float s_ks;
    __shared__ float s_thr;

    int tid = threadIdx.x;
    for (int i = tid; i < NBIN_A; i += 256) h[i] = 0u;
    __syncthreads();

    int gid = blockIdx.x * 256 + tid;
    int wv = gid >> 6, lane = gid & 63;
    size_t g = (size_t)wv * 4096 + lane;      // 1KB contiguous per wave
    float4 x4 = L4[g];
    float4 t4 = T4[g];
    float xs[4] = {x4.x, x4.y, x4.z, x4.w};
    float ts[4] = {t4.x, t4.y, t4.z, t4.w};
    uint nneg = 0;
    #pragma unroll
    for (int j = 0; j < 4; ++j) {
        if (ts[j] <= 0.5f) {
            nneg++;
            float f = fmaxf(fmaf(xs[j], ASCALE, -XMINF * ASCALE), 0.0f);
            uint b = (uint)f;
            b = b > NBIN_A - 1 ? NBIN_A - 1 : b;
            atomicAdd(&h[b], 1u);
        }
    }
    __syncthreads();
    for (int i = tid; i < NBIN_A; i += 256) {
        uint c = h[i];
        if (c) atomicAdd(&g_hist[i], c);
    }
    #pragma unroll
    for (int off = 32; off > 0; off >>= 1) nneg += __shfl_down(nneg, off);
    if ((tid & 63) == 0) s_cnt[tid >> 6] = nneg;
    __syncthreads();
    if (tid == 0) {
        uint c = s_cnt[0] + s_cnt[1] + s_cnt[2] + s_cnt[3];
        if (c) atomicAdd(g_nneg, c);
        __threadfence();
        s_rank = atomicAdd(doneA, 1u);
    }
    __syncthreads();
    if (s_rank != GB_A - 1) return;

    // ---- last block: derive threshold (atomic reads for coherence) ----
    uint lc[4];
    uint tc = 0;
    #pragma unroll
    for (int j = 0; j < 4; ++j) {
        lc[j] = atomicAdd(&g_hist[tid * 4 + j], 0u);
        tc += lc[j];
    }
    sh_c[tid] = tc;
    __syncthreads();
    if (tid == 0) {
        uint rc = 0;
        for (int i = 255; i >= 0; --i) { suf[i] = rc; rc += sh_c[i]; }
        float nneg64 = 64.0f * (float)atomicAdd(g_nneg, 0u);
        float kest = rintf(0.1f * nneg64);
        if (kest < 1024.0f) kest = 1024.0f;
        s_ks = kest * INV64;                  // sampled-scale rank target
        s_thr = XMINF;                        // fallback: select all
    }
    __syncthreads();
    float ks = s_ks;
    float run = (float)suf[tid];
    #pragma unroll
    for (int j = 3; j >= 0; --j) {
        float c = (float)lc[j];
        if (c > 0.0f && run < ks && run + c >= ks)
            s_thr = XMINF + (float)(tid * 4 + j) * INV_ASCALE;
        run += c;
    }
    __syncthreads();
    if (tid == 0) *g_thr = s_thr;
}

// ---- B: main accumulation (R7's exact loop shape) + fused final ----
extern "C" __global__ __launch_bounds__(1024) void ohem_main_final(
    const float4* __restrict__ L4, const float4* __restrict__ T4,
    const float* __restrict__ g_thr,
    uint* g_pcnt, float* g_psum, uint* g_acnt, float* g_asum,
    uint* doneB, float* out, int n_total, int n8)
{
    __shared__ uint s_pc[16];
    __shared__ float s_ps[16];
    __shared__ uint s_ac[16];
    __shared__ float s_as[16];
    __shared__ uint s_rank;

    const float thr = *g_thr;
    uint pcnt = 0, acnt = 0;
    float psum = 0.0f, asum = 0.0f;
    const int stride = gridDim.x * blockDim.x;

    for (int i = blockIdx.x * blockDim.x + threadIdx.x; i < n8; i += stride) {
        float4 xa = L4[2 * i];
        float4 xb = L4[2 * i + 1];
        float4 ta = T4[2 * i];
        float4 tb = T4[2 * i + 1];
        float xs[8] = {xa.x, xa.y, xa.z, xa.w, xb.x, xb.y, xb.z, xb.w};
        float ts[8] = {ta.x, ta.y, ta.z, ta.w, tb.x, tb.y, tb.z, tb.w};
        #pragma unroll
        for (int j = 0; j < 8; ++j) {
            float x = xs[j];
            float sp = fmaxf(x, 0.0f) + __logf(1.0f + __expf(-fabsf(x)));
            bool pos = ts[j] > 0.5f;
            bool sel = (x >= thr) && !pos;
            pcnt += pos ? 1u : 0u;
            psum += pos ? (sp - x) : 0.0f;   // softplus(-x) = softplus(x) - x
            acnt += sel ? 1u : 0u;
            asum += sel ? sp : 0.0f;
        }
    }
    // scalar tail for n_total % 8 != 0 -- empty for this shape
    if (blockIdx.x == 0) {
        const float* Lf = (const float*)L4;
        const float* Tf = (const float*)T4;
        for (int t = n8 * 8 + threadIdx.x; t < n_total; t += 1024) {
            float x = Lf[t];
            float sp = fmaxf(x, 0.0f) + __logf(1.0f + __expf(-fabsf(x)));
            bool pos = Tf[t] > 0.5f;
            bool sel = (x >= thr) && !pos;
            pcnt += pos ? 1u : 0u;
            psum += pos ? (sp - x) : 0.0f;
            acnt += sel ? 1u : 0u;
            asum += sel ? sp : 0.0f;
        }
    }

    #pragma unroll
    for (int off = 32; off > 0; off >>= 1) {
        pcnt += __shfl_down(pcnt, off);
        psum += __shfl_down(psum, off);
        acnt += __shfl_down(acnt, off);
        asum += __shfl_down(asum, off);
    }
    int wv = threadIdx.x >> 6;
    if ((threadIdx.x & 63) == 0) {
        s_pc[wv] = pcnt; s_ps[wv] = psum;
        s_ac[wv] = acnt; s_as[wv] = asum;
    }
    __syncthreads();
    if (threadIdx.x == 0) {
        uint pc = 0, ac = 0; float ps = 0.0f, as = 0.0f;
        #pragma unroll
        for (int w = 0; w < 16; ++w) {
            pc += s_pc[w]; ps += s_ps[w]; ac += s_ac[w]; as += s_as[w];
        }
        if (pc) atomicAdd(g_pcnt, pc);
        atomicAdd(g_psum, ps);
        if (ac) atomicAdd(g_acnt, ac);
        atomicAdd(g_asum, as);
        __threadfence();
        s_rank = atomicAdd(doneB, 1u);
    }
    __syncthreads();
    if (s_rank != GB_M - 1) return;

    // ---- last finishing block: fold the scalar ----
    if (threadIdx.x == 0) {
        uint npos = atomicAdd(g_pcnt, 0u);
        float psv = atomicAdd(g_psum, 0.0f);
        uint ac   = atomicAdd(g_acnt, 0u);
        float asv = atomicAdd(g_asum, 0.0f);
        uint nneg = (uint)n_total - npos;
        float pos_mean = npos ? (psv / (float)npos) : 0.0f;
        float res;
        if (nneg == 0) {
            res = pos_mean;
        } else {
            float nf = (float)nneg;          // RNE, matches .astype(f32)
            float kf = rintf(0.1f * nf);     // RNE, matches jnp.round
            if (kf < 1024.0f) kf = 1024.0f;
            if (kf > nf) kf = nf;
            float spt = softplus_f(thr);
            float neg_sum = asv + (kf - (float)ac) * spt;  // boundary corr.
            res = pos_mean + neg_sum / kf;
        }
        out[0] = res;
    }
}

extern "C" void kernel_launch(void* const* d_in, const int* in_sizes, int n_in,
                              void* d_out, int out_size, void* d_ws, size_t ws_size,
                              hipStream_t stream) {
    const float4* L4 = (const float4*)d_in[0];
    const float4* T4 = (const float4*)d_in[1];
    float* out = (float*)d_out;
    int n_total = in_sizes[0];
    int n8 = n_total / 8;

    // ws layout (bytes): hist[1024] @0, nneg @4096, thr @4100, pcnt @4104,
    // psum @4108, acnt @4112, asum @4116, doneA @4120, doneB @4124
    uint*  g_hist = (uint*)d_ws;
    uint*  g_nneg = (uint*)((char*)d_ws + 4096);
    float* g_thr  = (float*)((char*)d_ws + 4100);
    uint*  g_pcnt = (uint*)((char*)d_ws + 4104);
    float* g_psum = (float*)((char*)d_ws + 4108);
    uint*  g_acnt = (uint*)((char*)d_ws + 4112);
    float* g_asum = (float*)((char*)d_ws + 4116);
    uint*  doneA  = (uint*)((char*)d_ws + 4120);
    uint*  doneB  = (uint*)((char*)d_ws + 4124);

    hipMemsetAsync(d_ws, 0, 4128, stream);

    ohem_sample_thresh<<<GB_A, 256, 0, stream>>>(L4, T4, g_hist, g_nneg,
                                                 g_thr, doneA);
    ohem_main_final<<<GB_M, 1024, 0, stream>>>(L4, T4, g_thr,
                                               g_pcnt, g_psum, g_acnt, g_asum,
                                               doneB, out, n_total, n8);
}

// Round 11
// 63.623 us; speedup vs baseline: 2.3840x; 1.3255x over previous
//
#include <hip/hip_runtime.h>
#include <hip/hip_bf16.h>
#include <math.h>

// OHEM BCE-with-logits, shape (4,1,192,192,192) f32, scalar f32 output.
//
// R11 == R3 (the measured optimum, 62.7 us): counts-only histogram of the
// negative logits (softplus is monotone, so top-k selection works on x
// directly). 4096 bins over [-8,8) -> bin width 1/256. neg_sum is
// reconstructed as sum_b count_b * softplus(bin_center_b); within-bin error
// <= half-width (2e-3) << 5.5e-2 tolerance.
//
// 10 rounds of evidence: the 226MB two-stream pass is pinned at ~4.2 TB/s
// effective in THIS access pattern (grid-stride 512x1024, 2-adjacent-float4
// per lane) and every alternative is equal or worse: u64 LDS atomics -1.4x,
// zero-DS ballot -1.4x, fully-coalesced layouts -2x, last-block fusion
// -15%, prefetch/occupancy/branch changes neutral. Warm (L3-served) and
// cold (HBM) replays run identically, so the floor is the request path,
// not data location. This structure is the empirical roofline.

#define NBINS 4096
#define XOFF 8.0f
#define BIN_SCALE 256.0f        // (x+8)*256 -> [0, 4096)
#define INV_BIN 0.00390625f     // 1/256

extern "C" __global__ __launch_bounds__(1024) void ohem_pass1(
    const float* __restrict__ logits, const float* __restrict__ targets,
    unsigned int* __restrict__ g_cnt,
    unsigned int* __restrict__ g_npos, float* __restrict__ g_psum,
    int n8, int n_total)
{
    __shared__ unsigned int h[NBINS];   // 16 KiB
    __shared__ unsigned int s_pcnt[16];
    __shared__ float s_psum[16];

    for (int i = threadIdx.x; i < NBINS; i += 1024) h[i] = 0u;
    __syncthreads();

    const float4* L4 = (const float4*)logits;
    const float4* T4 = (const float4*)targets;
    unsigned int pcnt = 0;
    float psum = 0.0f;
    const int stride = gridDim.x * blockDim.x;

    for (int i = blockIdx.x * blockDim.x + threadIdx.x; i < n8; i += stride) {
        float4 xa = L4[2 * i];
        float4 xb = L4[2 * i + 1];
        float4 ta = T4[2 * i];
        float4 tb = T4[2 * i + 1];
        float xs[8] = {xa.x, xa.y, xa.z, xa.w, xb.x, xb.y, xb.z, xb.w};
        float ts[8] = {ta.x, ta.y, ta.z, ta.w, tb.x, tb.y, tb.z, tb.w};
        #pragma unroll
        for (int j = 0; j < 8; ++j) {
            float x = xs[j];
            if (ts[j] > 0.5f) {
                // exact positive loss: softplus(-x), fast HW transcendentals
                pcnt++;
                psum += fmaxf(-x, 0.0f) + __logf(1.0f + __expf(-fabsf(x)));
            } else {
                float f = fmaxf(fmaf(x, BIN_SCALE, XOFF * BIN_SCALE), 0.0f);
                unsigned int bin = (unsigned int)f;
                bin = bin > NBINS - 1 ? NBINS - 1 : bin;
                atomicAdd(&h[bin], 1u);   // non-returning ds_add_u32
            }
        }
    }
    // tail (n_total % 8) -- not hit for this shape, kept for safety
    if (blockIdx.x == 0) {
        for (int i = n8 * 8 + threadIdx.x; i < n_total; i += 1024) {
            float x = logits[i], t = targets[i];
            if (t > 0.5f) {
                pcnt++;
                psum += fmaxf(-x, 0.0f) + __logf(1.0f + __expf(-fabsf(x)));
            } else {
                float f = fmaxf(fmaf(x, BIN_SCALE, XOFF * BIN_SCALE), 0.0f);
                unsigned int bin = (unsigned int)f;
                bin = bin > NBINS - 1 ? NBINS - 1 : bin;
                atomicAdd(&h[bin], 1u);
            }
        }
    }
    __syncthreads();

    // flush LDS histogram to global
    for (int i = threadIdx.x; i < NBINS; i += 1024) {
        unsigned int c = h[i];
        if (c) atomicAdd(&g_cnt[i], c);
    }

    // reduce positive count/sum: wave64 shuffle, then cross-wave via LDS
    #pragma unroll
    for (int off = 32; off > 0; off >>= 1) {
        pcnt += __shfl_down(pcnt, off);
        psum += __shfl_down(psum, off);
    }
    int wave = threadIdx.x >> 6;
    if ((threadIdx.x & 63) == 0) { s_pcnt[wave] = pcnt; s_psum[wave] = psum; }
    __syncthreads();
    if (threadIdx.x == 0) {
        unsigned int c = 0; float s = 0.0f;
        #pragma unroll
        for (int w = 0; w < 16; ++w) { c += s_pcnt[w]; s += s_psum[w]; }
        if (c) atomicAdd(g_npos, c);
        atomicAdd(g_psum, s);
    }
}

__device__ __forceinline__ float softplus_acc(float v) {
    return fmaxf(v, 0.0f) + log1pf(expf(-fabsf(v)));
}

extern "C" __global__ __launch_bounds__(256) void ohem_finalize(
    const unsigned int* __restrict__ g_cnt,
    const unsigned int* __restrict__ g_npos, const float* __restrict__ g_psum,
    float* __restrict__ out, int n_total)
{
    const int BPT = NBINS / 256; // 16 bins per thread
    __shared__ unsigned int sh_c[256];
    __shared__ float sh_s[256];
    __shared__ unsigned int suf_c[256];
    __shared__ float suf_s[256];

    int tid = threadIdx.x;
    unsigned int lc[BPT];
    float lloss[BPT];            // per-bin total loss: c * softplus(center)
    unsigned int tc = 0;
    float tsum = 0.0f;
    #pragma unroll
    for (int j = 0; j < BPT; ++j) {
        int b = tid * BPT + j;
        unsigned int c = g_cnt[b];
        lc[j] = c;
        float lb = 0.0f;
        if (c > 0) {
            float center = ((float)b + 0.5f) * INV_BIN - XOFF;
            lb = (float)c * softplus_acc(center);
        }
        lloss[j] = lb;
        tc += c;
        tsum += lb;
    }
    sh_c[tid] = tc;
    sh_s[tid] = tsum;
    __syncthreads();

    if (tid == 0) {
        // exclusive suffix totals over the 256 thread-chunks
        unsigned int rc = 0; float rs = 0.0f;
        for (int i = 255; i >= 0; --i) {
            suf_c[i] = rc; suf_s[i] = rs;
            rc += sh_c[i]; rs += sh_s[i];
        }
    }
    __syncthreads();

    unsigned int n_pos = *g_npos;
    unsigned int n_neg = (unsigned int)n_total - n_pos;
    float pos_mean = (n_pos > 0) ? (*g_psum / (float)n_pos) : 0.0f;

    if (n_neg == 0) {
        if (tid == 0) out[0] = pos_mean;
        return;
    }

    // k = max(1024, rint(0.1 * n_neg)), clamped to n_neg (RNE matches jnp.round)
    float nf = (float)n_neg;
    int k = (int)rintf(nf * 0.1f);
    if (k < 1024) k = 1024;
    if ((unsigned int)k > n_neg) k = (int)n_neg;

    // walk own chunk from the top bin down; exactly one (tid, j) crosses k
    unsigned int run_c = suf_c[tid];
    float run_s = suf_s[tid];
    #pragma unroll
    for (int j = BPT - 1; j >= 0; --j) {
        unsigned int c = lc[j];
        float lb = lloss[j];
        if (c > 0 && run_c < (unsigned int)k && run_c + c >= (unsigned int)k) {
            unsigned int m = (unsigned int)k - run_c;
            float neg_sum = run_s + (float)m * (lb / (float)c);
            float neg_mean = neg_sum / (float)k;
            out[0] = pos_mean + neg_mean;
        }
        run_c += c;
        run_s += lb;
    }
}

extern "C" void kernel_launch(void* const* d_in, const int* in_sizes, int n_in,
                              void* d_out, int out_size, void* d_ws, size_t ws_size,
                              hipStream_t stream) {
    const float* logits  = (const float*)d_in[0];
    const float* targets = (const float*)d_in[1];
    float* out = (float*)d_out;
    int n_total = in_sizes[0];
    int n8 = n_total / 8;

    unsigned int* g_cnt  = (unsigned int*)d_ws;
    unsigned int* g_npos = (unsigned int*)((char*)d_ws + NBINS * 4);
    float*        g_psum = (float*)((char*)d_ws + NBINS * 4 + 4);

    hipMemsetAsync(d_ws, 0, NBINS * 4 + 8, stream);

    // 1024-thread blocks: 512 blocks = 2 blocks/CU * 16 waves = full residency
    ohem_pass1<<<512, 1024, 0, stream>>>(logits, targets, g_cnt,
                                         g_npos, g_psum, n8, n_total);
    ohem_finalize<<<1, 256, 0, stream>>>(g_cnt, g_npos, g_psum, out, n_total);
}